// Round 27
// baseline (95.348 us; speedup 1.0000x reference)
//
#include <hip/hip_runtime.h>
#include <hip/hip_fp16.h>
#include <math.h>
#include <stdint.h>
#include <string.h>

typedef unsigned __int128 u128;
typedef _Float16 h2v __attribute__((ext_vector_type(2)));
typedef short    s2v __attribute__((ext_vector_type(2)));

#define NK 10000
#define KPB 8              // one k per wave; grid = NK/KPB = 1250

#define PCG_MUL_128 ((((u128)0x2360ed051fc65da4ULL) << 64) | 0x4385df649fccf645ULL)

#define WS_NEEDED  (NK * 4)

struct ThrTab { double t[3][84]; };        // dil thresholds, v = 2..85

// ============================================================================
// numpy default_rng(0) chain (verified r8-r26): SeedSequence mix = x*L - y*R
// (SUBTRACT); PCG64 XSL-RR step-then-output; integers -> buffered Lemire32,
// low half first. Device regenerates draws per-thread via advance() skip-ahead.
// ============================================================================
static void host_seed(u128& state, u128& inc) {
  uint32_t hc = 0x43b0d7e5u;
  auto hashmix = [&hc](uint32_t v) -> uint32_t {
    v ^= hc; hc *= 0x931e8875u; v *= hc; v ^= v >> 16; return v;
  };
  uint32_t pool[4];
  for (int i = 0; i < 4; ++i) pool[i] = hashmix(0u);
  for (int s = 0; s < 4; ++s)
    for (int d = 0; d < 4; ++d)
      if (s != d) {
        uint32_t h = hashmix(pool[s]);
        uint32_t r = pool[d] * 0xca01f9ddu - h * 0x4973f715u;   // subtract
        r ^= r >> 16;
        pool[d] = r;
      }
  uint32_t hb = 0x8b51f9ddu;
  uint32_t w[8];
  for (int i = 0; i < 8; ++i) {
    uint32_t v = pool[i & 3];
    v ^= hb; hb *= 0x58f38dedu; v *= hb; v ^= v >> 16;
    w[i] = v;
  }
  u128 is_ = ((u128)(((uint64_t)w[0]) | ((uint64_t)w[1] << 32)) << 64)
           | (u128)(((uint64_t)w[2]) | ((uint64_t)w[3] << 32));
  u128 iq  = ((u128)(((uint64_t)w[4]) | ((uint64_t)w[5] << 32)) << 64)
           | (u128)(((uint64_t)w[6]) | ((uint64_t)w[7] << 32));
  inc = (iq << 1) | (u128)1;
  state = inc; state += is_; state = state * PCG_MUL_128 + inc;
}

static inline uint64_t xslrr_h(u128 s) {
  uint64_t x = (uint64_t)(s >> 64) ^ (uint64_t)s;
  unsigned r = (unsigned)(s >> 122);
  return (x >> r) | (x << ((64u - r) & 63u));
}

__device__ __forceinline__ void dev_seed(u128& state, u128& inc) {
  uint32_t hc = 0x43b0d7e5u;
  auto hashmix = [&hc](uint32_t v) -> uint32_t {
    v ^= hc; hc *= 0x931e8875u; v *= hc; v ^= v >> 16; return v;
  };
  uint32_t pool[4];
  for (int i = 0; i < 4; ++i) pool[i] = hashmix(0u);
  for (int s = 0; s < 4; ++s)
    for (int d = 0; d < 4; ++d)
      if (s != d) {
        uint32_t h = hashmix(pool[s]);
        uint32_t r = pool[d] * 0xca01f9ddu - h * 0x4973f715u;   // subtract
        r ^= r >> 16;
        pool[d] = r;
      }
  uint32_t hb = 0x8b51f9ddu;
  uint32_t w[8];
  for (int i = 0; i < 8; ++i) {
    uint32_t v = pool[i & 3];
    v ^= hb; hb *= 0x58f38dedu; v *= hb; v ^= v >> 16;
    w[i] = v;
  }
  u128 is_ = ((u128)(((uint64_t)w[0]) | ((uint64_t)w[1] << 32)) << 64)
           | (u128)(((uint64_t)w[2]) | ((uint64_t)w[3] << 32));
  u128 iq  = ((u128)(((uint64_t)w[4]) | ((uint64_t)w[5] << 32)) << 64)
           | (u128)(((uint64_t)w[6]) | ((uint64_t)w[7] << 32));
  inc = (iq << 1) | (u128)1;
  state = inc; state += is_; state = state * PCG_MUL_128 + inc;
}

__device__ __forceinline__ u128 dev_advance(u128 state, u128 inc, uint64_t delta) {
  u128 am = 1, ap = 0, cm = PCG_MUL_128, cp = inc;
  while (delta) {
    if (delta & 1) { am = am * cm; ap = ap * cm + cp; }
    cp = (cm + (u128)1) * cp;
    cm = cm * cm;
    delta >>= 1;
  }
  return am * state + ap;
}

__device__ __forceinline__ uint64_t draw_at(u128 state, u128 inc, uint64_t n) {
  u128 s = dev_advance(state, inc, n);
  s = s * PCG_MUL_128 + inc;                // step-then-output
  uint64_t x = (uint64_t)(s >> 64) ^ (uint64_t)s;
  unsigned r = (unsigned)(s >> 122);
  return (x >> r) | (x << ((64u - r) & 63u));
}

// ============================================================================
// params_k: 40 blocks x 256, one entry per thread, PLUS block-local counting
// sort by L descending (hist + 256-wide scan + scatter). Each 256-entry
// segment is internally L-sorted; conv blocks take 8 consecutive entries
// (256 % 8 == 0) -> balanced waves without a separate global sort pass.
// ============================================================================
__global__ __launch_bounds__(256) void params_k(uint32_t* __restrict__ pack,
                                                ThrTab tt) {
  __shared__ int hist[1024];
  __shared__ int scanbuf[256];
  __shared__ int offs[1024];
  int tid = threadIdx.x;
  int base = blockIdx.x * 256;
  int n = NK - base; if (n > 256) n = 256;

  uint32_t e = 0;
  int bkt = -1;
  if (tid < n) {
    int i = base + tid;
    u128 state, inc;
    dev_seed(state, inc);
    uint64_t a = draw_at(state, inc, (uint64_t)(i >> 1));
    uint32_t u = (i & 1) ? (uint32_t)(a >> 32) : (uint32_t)a;
    int si = (int)(((uint64_t)u * 3ull) >> 32);
    uint64_t ud = draw_at(state, inc, (uint64_t)(5000 + i));
    double d = (double)(ud >> 11) * (1.0 / 9007199254740992.0);
    int c0 = 0, c1 = 0, c2 = 0;
    #pragma unroll
    for (int v = 0; v < 84; ++v) {
      c0 += (d >= tt.t[0][v]) ? 1 : 0;
      c1 += (d >= tt.t[1][v]) ? 1 : 0;
      c2 += (d >= tt.t[2][v]) ? 1 : 0;
    }
    int dil = 1 + ((si == 0) ? c0 : ((si == 1) ? c1 : c2));
    uint64_t p6 = draw_at(state, inc, (uint64_t)(15000 + (i >> 1)));
    uint32_t pu = (i & 1) ? (uint32_t)(p6 >> 32) : (uint32_t)p6;
    int pad = (int)(pu >> 31);
    int ks = 7 + 2 * si;
    int twop = (ks - 1) * dil * pad;
    int L = 512 + 2 * twop - dil * (ks - 1);
    e = ((uint32_t)i << 10) | (uint32_t)si | ((uint32_t)dil << 2)
      | ((uint32_t)pad << 9);
    bkt = 1022 - L;                         // L in [2,1022] -> [0,1020]
  }
  #pragma unroll
  for (int q = 0; q < 4; ++q) hist[tid + 256 * q] = 0;
  __syncthreads();
  if (bkt >= 0) atomicAdd(&hist[bkt], 1);
  __syncthreads();
  int h0 = hist[4 * tid], h1 = hist[4 * tid + 1];
  int h2 = hist[4 * tid + 2], h3 = hist[4 * tid + 3];
  int s = h0 + h1 + h2 + h3;
  scanbuf[tid] = s;
  __syncthreads();
  for (int off = 1; off < 256; off <<= 1) {  // Hillis-Steele inclusive
    int v = (tid >= off) ? scanbuf[tid - off] : 0;
    __syncthreads();
    scanbuf[tid] += v;
    __syncthreads();
  }
  int ex = scanbuf[tid] - s;                 // exclusive prefix of group
  offs[4 * tid]     = ex;
  offs[4 * tid + 1] = ex + h0;
  offs[4 * tid + 2] = ex + h0 + h1;
  offs[4 * tid + 3] = ex + h0 + h1 + h2;
  __syncthreads();
  if (bkt >= 0) {
    int idx = atomicAdd(&offs[bkt], 1);
    pack[base + idx] = e;
  }
}

// ============================================================================
// Conv + max/ppv (r26-proven): FP16-LDS xs[t][16 batches] (32 B/row, row 512
// = zeros); lane (tl=lane>>1, bh=lane&1) reads float4 = 4 half2 = 8 batches
// at one t (conflict-free ds_read_b128). MAC chain = __hfma2 (bias in acc
// init); chunk epilogue = packed v_pk_max_f16 + mask-subtract.
// ============================================================================
template<int KS>
__device__ __forceinline__ void conv_core(const float4* __restrict__ xs4,
                                          const __half2* wh2, __half2 bvh2,
                                          int twop, int dil, int L,
                                          int tl, int bh,
                                          h2v* mh, s2v* ch) {
  const h2v zero2 = (h2v)0;
  int coreEnd = (L < 512) ? L : 512;
  int nch = (L + 31) >> 5;
  for (int c = 0; c < nch; ++c) {
    int t0 = c << 5;
    int t = t0 + tl;
    __half2 acc[4];
    #pragma unroll
    for (int r = 0; r < 4; ++r) acc[r] = bvh2;
    if (t0 >= twop && t0 + 32 <= coreEnd) {
      // fast path: every tap in-range; pointer walk, no clamps
      const float4* p = xs4 + (unsigned)(t - twop) * 2 + bh;
      #pragma unroll
      for (int j = 0; j < KS; ++j) {
        float4 v4 = *p;
        union { float4 v; __half2 h[4]; } u;
        u.v = v4;
        __half2 wj = wh2[j];
        #pragma unroll
        for (int r = 0; r < 4; ++r) acc[r] = __hfma2(wj, u.h[r], acc[r]);
        p += (unsigned)dil * 2;
      }
    } else {
      // boundary chunk: umin clamp to zero row (negatives wrap -> 512)
      int idx = t - twop;
      #pragma unroll
      for (int j = 0; j < KS; ++j) {
        unsigned ci = (unsigned)idx;
        ci = (ci > 512u) ? 512u : ci;
        float4 v4 = xs4[ci * 2 + bh];
        union { float4 v; __half2 h[4]; } u;
        u.v = v4;
        __half2 wj = wh2[j];
        #pragma unroll
        for (int r = 0; r < 4; ++r) acc[r] = __hfma2(wj, u.h[r], acc[r]);
        idx += dil;
      }
    }
    if (t < L) {
      #pragma unroll
      for (int r = 0; r < 4; ++r) {
        union { __half2 h; h2v v; } cv;
        cv.h = acc[r];
        mh[r] = __builtin_elementwise_max(mh[r], cv.v);
        ch[r] -= (cv.v > zero2);             // mask = -1 per true -> +1
      }
    }
  }
}

__global__ __launch_bounds__(512) void conv_feat_k(const float* __restrict__ x,
                                                   const float* __restrict__ W,
                                                   const float* __restrict__ bias,
                                                   const uint32_t* __restrict__ entries,
                                                   float failDiag,
                                                   float* __restrict__ out) {
  __shared__ float4 xs4[513 * 2];    // 16 halves per t; row 512 = zeros (16.4 KB)
  int tid = threadIdx.x;

  // stage batch-transposed fp16, once per block: flat = t*2 + bh
  #pragma unroll
  for (int q = 0; q < 2; ++q) {
    int flat = q * 512 + tid;        // 0..1023
    int t = flat >> 1, bh = flat & 1;
    union { __half h[8]; float4 v; } u;
    #pragma unroll
    for (int r = 0; r < 8; ++r)
      u.h[r] = __float2half(x[(8 * bh + r) * 512 + t]);
    xs4[flat] = u.v;
  }
  if (tid < 2) xs4[512 * 2 + tid] = make_float4(0.f, 0.f, 0.f, 0.f);

  int wave = tid >> 6, lane = tid & 63;
  int tl = lane >> 1, bh = lane & 1;
  uint32_t e = entries[blockIdx.x * KPB + wave];
  int k = (int)(e >> 10);
  uint32_t bits = e & 1023u;
  __syncthreads();                   // the only barrier

  int ks  = 7 + 2 * (int)(bits & 3);
  int dil = (int)((bits >> 2) & 127);
  int pad = (int)(bits >> 9);
  int twop = (ks - 1) * dil * pad;
  int L = 512 + 2 * twop - dil * (ks - 1);
  float w10 = W[k * 11 + 10], w8 = W[k * 11 + 8];
  int ksW = (w10 != 0.0f) ? 11 : ((w8 != 0.0f) ? 9 : 7);
  if (failDiag != 0.0f || ks != ksW) {   // diag (never taken when correct)
    float diag = (failDiag != 0.0f) ? failDiag : 6500000.0f;
    if (lane < 16) {
      out[(size_t)lane * 20000 + 2 * k]     = diag;
      out[(size_t)lane * 20000 + 2 * k + 1] = diag;
    }
    return;
  }

  __half2 wh2[11];
  #pragma unroll
  for (int j = 0; j < 11; ++j) wh2[j] = __float2half2_rn(W[k * 11 + j]);
  __half2 bvh2 = __float2half2_rn(bias[k]);

  h2v mh[4];
  s2v ch[4];
  #pragma unroll
  for (int r = 0; r < 4; ++r) {
    mh[r] = (h2v)(-__builtin_huge_valf16());
    ch[r] = (s2v)0;
  }
  if (ks == 7)       conv_core<7>(xs4, wh2, bvh2, twop, dil, L, tl, bh, mh, ch);
  else if (ks == 9)  conv_core<9>(xs4, wh2, bvh2, twop, dil, L, tl, bh, mh, ch);
  else               conv_core<11>(xs4, wh2, bvh2, twop, dil, L, tl, bh, mh, ch);

  float m[8];
  int cn[8];
  #pragma unroll
  for (int r = 0; r < 4; ++r) {
    m[2 * r]      = (float)mh[r].x;
    m[2 * r + 1]  = (float)mh[r].y;
    cn[2 * r]     = (int)ch[r].x;
    cn[2 * r + 1] = (int)ch[r].y;
  }
  // reduce over tl (lane bits 1..5); bh (bit 0) preserved
  #pragma unroll
  for (int off = 2; off <= 32; off <<= 1) {
    #pragma unroll
    for (int r = 0; r < 8; ++r) {
      m[r] = fmaxf(m[r], __shfl_xor(m[r], off));
      cn[r] += __shfl_xor(cn[r], off);
    }
  }
  if (tl == 0) {                     // lanes 0,1 hold batches 8*bh + r
    float invL = 1.0f / (float)L;
    #pragma unroll
    for (int r = 0; r < 8; ++r) {
      size_t b = (size_t)(8 * bh + r);
      out[b * 20000 + 2 * k]     = m[r];
      out[b * 20000 + 2 * k + 1] = (float)cn[r] * invL;
    }
  }
}

extern "C" void kernel_launch(void* const* d_in, const int* in_sizes, int n_in,
                              void* d_out, int out_size, void* d_ws, size_t ws_size,
                              hipStream_t stream) {
  (void)out_size;
  const float *x = nullptr, *W = nullptr, *bias = nullptr;
  for (int i = 0; i < n_in; ++i) {
    int sz = in_sizes[i];
    if (sz == 16 * 512)      x    = (const float*)d_in[i];
    else if (sz == NK * 11)  W    = (const float*)d_in[i];
    else if (sz == NK)       bias = (const float*)d_in[i];
  }
  float failDiag = 0.0f;
  if (!x || !W || !bias) {
    failDiag = 9000000.0f;
    x = (const float*)d_in[0]; W = (const float*)d_in[1]; bias = (const float*)d_in[2];
  }

  // host stream for oracle + rejection check (off the timed path)
  static uint64_t hs[20000];
  {
    u128 st, inc; host_seed(st, inc);
    for (int i = 0; i < 20000; ++i) { st = st * PCG_MUL_128 + inc; hs[i] = xslrr_h(st); }
  }
  double d0 = (double)(hs[0] >> 11) * (1.0 / 9007199254740992.0);
  if (failDiag == 0.0f && fabs(d0 - 0.6369616873214543) >= 1.0e-15)
    failDiag = 4000000.0f;
  int rejected = 0;
  for (int i = 0; i < 5000; ++i)
    if ((uint32_t)hs[i] == 0u || (uint32_t)(hs[i] >> 32) == 0u) { rejected = 1; break; }

  // exact dil thresholds: t[si][v-2] = min d with pow(2, hi*d) >= v (glibc)
  static ThrTab tt;
  for (int si = 0; si < 3; ++si) {
    int ksv = 7 + 2 * si;
    double hi = log2((double)(511 / (ksv - 1)));
    double dmax = nextafter(1.0, 0.0);
    for (int v = 2; v <= 85; ++v) {
      if (pow(2.0, hi * dmax) < (double)v) { tt.t[si][v - 2] = 2.0; continue; }
      uint64_t lo = 0, hb;
      memcpy(&hb, &dmax, 8);
      while (hb - lo > 1) {
        uint64_t mid = lo + (hb - lo) / 2;
        double dm;
        memcpy(&dm, &mid, 8);
        if (pow(2.0, hi * dm) >= (double)v) hb = mid; else lo = mid;
      }
      double tv;
      memcpy(&tv, &hb, 8);
      tt.t[si][v - 2] = tv;
    }
  }

  uint32_t* dpack = (uint32_t*)d_ws;

  if (!rejected && ws_size >= WS_NEEDED) {
    params_k<<<(NK + 255) / 256, 256, 0, stream>>>(dpack, tt);
    conv_feat_k<<<NK / KPB, 512, 0, stream>>>(x, W, bias, dpack, failDiag,
                                              (float*)d_out);
  } else {
    // fallback (never for this seed): host pack + global sort, one 40 KB H2D
    static uint32_t h_entries[NK];
    {
      int pos32 = 0;
      auto nx32 = [&](int& p) -> uint32_t {
        uint64_t v = hs[p >> 1];
        uint32_t u = (p & 1) ? (uint32_t)(v >> 32) : (uint32_t)v;
        ++p; return u;
      };
      static int ksA[NK], dilA[NK], padA[NK];
      for (int i = 0; i < NK; ++i) {
        uint64_t m; uint32_t u;
        do { u = nx32(pos32); m = (uint64_t)u * 3ull; } while ((uint32_t)m == 0u);
        ksA[i] = (int)(m >> 32);
      }
      int u64pos = (pos32 + 1) >> 1;
      for (int i = 0; i < NK; ++i) {
        double d = (double)(hs[u64pos + i] >> 11) * (1.0 / 9007199254740992.0);
        int ksv = 7 + 2 * ksA[i];
        double hi2 = log2((double)(511 / (ksv - 1)));
        dilA[i] = (int)floor(pow(2.0, hi2 * d));
      }
      int p32 = 2 * (u64pos + NK);
      for (int i = 0; i < NK; ++i) padA[i] = (int)(nx32(p32) >> 31);
      static int cnt2[1024], off2[1024];
      for (int b = 0; b < 1024; ++b) cnt2[b] = 0;
      for (int i = 0; i < NK; ++i) {
        int ksv = 7 + 2 * ksA[i];
        int twop = (ksv - 1) * dilA[i] * padA[i];
        int L = 512 + 2 * twop - dilA[i] * (ksv - 1);
        cnt2[1022 - L]++;
      }
      int acc = 0;
      for (int b = 0; b < 1024; ++b) { off2[b] = acc; acc += cnt2[b]; }
      for (int i = 0; i < NK; ++i) {
        int ksv = 7 + 2 * ksA[i];
        int twop = (ksv - 1) * dilA[i] * padA[i];
        int L = 512 + 2 * twop - dilA[i] * (ksv - 1);
        uint32_t bits = (uint32_t)ksA[i] | ((uint32_t)dilA[i] << 2)
                      | ((uint32_t)padA[i] << 9);
        h_entries[off2[1022 - L]++] = ((uint32_t)i << 10) | bits;
      }
    }
    (void)hipMemcpyAsync(dpack, h_entries, sizeof(h_entries),
                         hipMemcpyHostToDevice, stream);
    conv_feat_k<<<NK / KPB, 512, 0, stream>>>(x, W, bias, dpack, failDiag,
                                              (float*)d_out);
  }
}

// Round 28
// 61.893 us; speedup vs baseline: 1.5405x; 1.5405x over previous
//
#include <hip/hip_runtime.h>
#include <hip/hip_fp16.h>
#include <math.h>
#include <stdint.h>
#include <string.h>

typedef unsigned __int128 u128;
typedef _Float16 h2v __attribute__((ext_vector_type(2)));
typedef short    s2v __attribute__((ext_vector_type(2)));

#define NK 10000
#define KPB 8              // one k per wave; grid = NK/KPB = 1250

#define PCG_MUL_128 ((((u128)0x2360ed051fc65da4ULL) << 64) | 0x4385df649fccf645ULL)

#define WS_NEEDED  (NK * 4)

struct ThrTab { double t[3][84]; };        // dil thresholds, v = 2..85

// ============================================================================
// numpy default_rng(0) chain (verified r8-r27): SeedSequence mix = x*L - y*R
// (SUBTRACT); PCG64 XSL-RR step-then-output; integers -> buffered Lemire32,
// low half first. Device regenerates draws per-thread via advance() skip-ahead.
// ============================================================================
static void host_seed(u128& state, u128& inc) {
  uint32_t hc = 0x43b0d7e5u;
  auto hashmix = [&hc](uint32_t v) -> uint32_t {
    v ^= hc; hc *= 0x931e8875u; v *= hc; v ^= v >> 16; return v;
  };
  uint32_t pool[4];
  for (int i = 0; i < 4; ++i) pool[i] = hashmix(0u);
  for (int s = 0; s < 4; ++s)
    for (int d = 0; d < 4; ++d)
      if (s != d) {
        uint32_t h = hashmix(pool[s]);
        uint32_t r = pool[d] * 0xca01f9ddu - h * 0x4973f715u;   // subtract
        r ^= r >> 16;
        pool[d] = r;
      }
  uint32_t hb = 0x8b51f9ddu;
  uint32_t w[8];
  for (int i = 0; i < 8; ++i) {
    uint32_t v = pool[i & 3];
    v ^= hb; hb *= 0x58f38dedu; v *= hb; v ^= v >> 16;
    w[i] = v;
  }
  u128 is_ = ((u128)(((uint64_t)w[0]) | ((uint64_t)w[1] << 32)) << 64)
           | (u128)(((uint64_t)w[2]) | ((uint64_t)w[3] << 32));
  u128 iq  = ((u128)(((uint64_t)w[4]) | ((uint64_t)w[5] << 32)) << 64)
           | (u128)(((uint64_t)w[6]) | ((uint64_t)w[7] << 32));
  inc = (iq << 1) | (u128)1;
  state = inc; state += is_; state = state * PCG_MUL_128 + inc;
}

static inline uint64_t xslrr_h(u128 s) {
  uint64_t x = (uint64_t)(s >> 64) ^ (uint64_t)s;
  unsigned r = (unsigned)(s >> 122);
  return (x >> r) | (x << ((64u - r) & 63u));
}

__device__ __forceinline__ void dev_seed(u128& state, u128& inc) {
  uint32_t hc = 0x43b0d7e5u;
  auto hashmix = [&hc](uint32_t v) -> uint32_t {
    v ^= hc; hc *= 0x931e8875u; v *= hc; v ^= v >> 16; return v;
  };
  uint32_t pool[4];
  for (int i = 0; i < 4; ++i) pool[i] = hashmix(0u);
  for (int s = 0; s < 4; ++s)
    for (int d = 0; d < 4; ++d)
      if (s != d) {
        uint32_t h = hashmix(pool[s]);
        uint32_t r = pool[d] * 0xca01f9ddu - h * 0x4973f715u;   // subtract
        r ^= r >> 16;
        pool[d] = r;
      }
  uint32_t hb = 0x8b51f9ddu;
  uint32_t w[8];
  for (int i = 0; i < 8; ++i) {
    uint32_t v = pool[i & 3];
    v ^= hb; hb *= 0x58f38dedu; v *= hb; v ^= v >> 16;
    w[i] = v;
  }
  u128 is_ = ((u128)(((uint64_t)w[0]) | ((uint64_t)w[1] << 32)) << 64)
           | (u128)(((uint64_t)w[2]) | ((uint64_t)w[3] << 32));
  u128 iq  = ((u128)(((uint64_t)w[4]) | ((uint64_t)w[5] << 32)) << 64)
           | (u128)(((uint64_t)w[6]) | ((uint64_t)w[7] << 32));
  inc = (iq << 1) | (u128)1;
  state = inc; state += is_; state = state * PCG_MUL_128 + inc;
}

__device__ __forceinline__ u128 dev_advance(u128 state, u128 inc, uint64_t delta) {
  u128 am = 1, ap = 0, cm = PCG_MUL_128, cp = inc;
  while (delta) {
    if (delta & 1) { am = am * cm; ap = ap * cm + cp; }
    cp = (cm + (u128)1) * cp;
    cm = cm * cm;
    delta >>= 1;
  }
  return am * state + ap;
}

__device__ __forceinline__ uint64_t draw_at(u128 state, u128 inc, uint64_t n) {
  u128 s = dev_advance(state, inc, n);
  s = s * PCG_MUL_128 + inc;                // step-then-output
  uint64_t x = (uint64_t)(s >> 64) ^ (uint64_t)s;
  unsigned r = (unsigned)(s >> 122);
  return (x >> r) | (x << ((64u - r) & 63u));
}

// ============================================================================
// params_k (r27-proven): 40 blocks x 256, one entry per thread + block-local
// counting sort by L descending (hist + scan + scatter into pack segment).
// ============================================================================
__global__ __launch_bounds__(256) void params_k(uint32_t* __restrict__ pack,
                                                ThrTab tt) {
  __shared__ int hist[1024];
  __shared__ int scanbuf[256];
  __shared__ int offs[1024];
  int tid = threadIdx.x;
  int base = blockIdx.x * 256;
  int n = NK - base; if (n > 256) n = 256;

  uint32_t e = 0;
  int bkt = -1;
  if (tid < n) {
    int i = base + tid;
    u128 state, inc;
    dev_seed(state, inc);
    uint64_t a = draw_at(state, inc, (uint64_t)(i >> 1));
    uint32_t u = (i & 1) ? (uint32_t)(a >> 32) : (uint32_t)a;
    int si = (int)(((uint64_t)u * 3ull) >> 32);
    uint64_t ud = draw_at(state, inc, (uint64_t)(5000 + i));
    double d = (double)(ud >> 11) * (1.0 / 9007199254740992.0);
    int c0 = 0, c1 = 0, c2 = 0;
    #pragma unroll
    for (int v = 0; v < 84; ++v) {
      c0 += (d >= tt.t[0][v]) ? 1 : 0;
      c1 += (d >= tt.t[1][v]) ? 1 : 0;
      c2 += (d >= tt.t[2][v]) ? 1 : 0;
    }
    int dil = 1 + ((si == 0) ? c0 : ((si == 1) ? c1 : c2));
    uint64_t p6 = draw_at(state, inc, (uint64_t)(15000 + (i >> 1)));
    uint32_t pu = (i & 1) ? (uint32_t)(p6 >> 32) : (uint32_t)p6;
    int pad = (int)(pu >> 31);
    int ks = 7 + 2 * si;
    int twop = (ks - 1) * dil * pad;
    int L = 512 + 2 * twop - dil * (ks - 1);
    e = ((uint32_t)i << 10) | (uint32_t)si | ((uint32_t)dil << 2)
      | ((uint32_t)pad << 9);
    bkt = 1022 - L;                         // L in [2,1022] -> [0,1020]
  }
  #pragma unroll
  for (int q = 0; q < 4; ++q) hist[tid + 256 * q] = 0;
  __syncthreads();
  if (bkt >= 0) atomicAdd(&hist[bkt], 1);
  __syncthreads();
  int h0 = hist[4 * tid], h1 = hist[4 * tid + 1];
  int h2 = hist[4 * tid + 2], h3 = hist[4 * tid + 3];
  int s = h0 + h1 + h2 + h3;
  scanbuf[tid] = s;
  __syncthreads();
  for (int off = 1; off < 256; off <<= 1) {  // Hillis-Steele inclusive
    int v = (tid >= off) ? scanbuf[tid - off] : 0;
    __syncthreads();
    scanbuf[tid] += v;
    __syncthreads();
  }
  int ex = scanbuf[tid] - s;                 // exclusive prefix of group
  offs[4 * tid]     = ex;
  offs[4 * tid + 1] = ex + h0;
  offs[4 * tid + 2] = ex + h0 + h1;
  offs[4 * tid + 3] = ex + h0 + h1 + h2;
  __syncthreads();
  if (bkt >= 0) {
    int idx = atomicAdd(&offs[bkt], 1);
    pack[base + idx] = e;
  }
}

// ============================================================================
// Conv + max/ppv (r26-proven body). Block -> entry mapping is POS-MAJOR
// across the 40 locally-sorted segments (LPT dispatch): blocks 0..39 take
// every segment's longest-L group first; drain-phase blocks are all tiny.
//   b < 80:  pos = b/40, seg = b%40        (pos 0..1, all 40 segments)
//   b >= 80: pos = 2+(b-80)/39, seg = (b-80)%39  (segment 39 has 16 entries)
// Bijective onto entries 0..9999.
// ============================================================================
template<int KS>
__device__ __forceinline__ void conv_core(const float4* __restrict__ xs4,
                                          const __half2* wh2, __half2 bvh2,
                                          int twop, int dil, int L,
                                          int tl, int bh,
                                          h2v* mh, s2v* ch) {
  const h2v zero2 = (h2v)0;
  int coreEnd = (L < 512) ? L : 512;
  int nch = (L + 31) >> 5;
  for (int c = 0; c < nch; ++c) {
    int t0 = c << 5;
    int t = t0 + tl;
    __half2 acc[4];
    #pragma unroll
    for (int r = 0; r < 4; ++r) acc[r] = bvh2;
    if (t0 >= twop && t0 + 32 <= coreEnd) {
      // fast path: every tap in-range; pointer walk, no clamps
      const float4* p = xs4 + (unsigned)(t - twop) * 2 + bh;
      #pragma unroll
      for (int j = 0; j < KS; ++j) {
        float4 v4 = *p;
        union { float4 v; __half2 h[4]; } u;
        u.v = v4;
        __half2 wj = wh2[j];
        #pragma unroll
        for (int r = 0; r < 4; ++r) acc[r] = __hfma2(wj, u.h[r], acc[r]);
        p += (unsigned)dil * 2;
      }
    } else {
      // boundary chunk: umin clamp to zero row (negatives wrap -> 512)
      int idx = t - twop;
      #pragma unroll
      for (int j = 0; j < KS; ++j) {
        unsigned ci = (unsigned)idx;
        ci = (ci > 512u) ? 512u : ci;
        float4 v4 = xs4[ci * 2 + bh];
        union { float4 v; __half2 h[4]; } u;
        u.v = v4;
        __half2 wj = wh2[j];
        #pragma unroll
        for (int r = 0; r < 4; ++r) acc[r] = __hfma2(wj, u.h[r], acc[r]);
        idx += dil;
      }
    }
    if (t < L) {
      #pragma unroll
      for (int r = 0; r < 4; ++r) {
        union { __half2 h; h2v v; } cv;
        cv.h = acc[r];
        mh[r] = __builtin_elementwise_max(mh[r], cv.v);
        ch[r] -= (cv.v > zero2);             // mask = -1 per true -> +1
      }
    }
  }
}

__global__ __launch_bounds__(512) void conv_feat_k(const float* __restrict__ x,
                                                   const float* __restrict__ W,
                                                   const float* __restrict__ bias,
                                                   const uint32_t* __restrict__ entries,
                                                   float failDiag,
                                                   float* __restrict__ out) {
  __shared__ float4 xs4[513 * 2];    // 16 halves per t; row 512 = zeros (16.4 KB)
  int tid = threadIdx.x;

  // stage batch-transposed fp16, once per block: flat = t*2 + bh
  #pragma unroll
  for (int q = 0; q < 2; ++q) {
    int flat = q * 512 + tid;        // 0..1023
    int t = flat >> 1, bh = flat & 1;
    union { __half h[8]; float4 v; } u;
    #pragma unroll
    for (int r = 0; r < 8; ++r)
      u.h[r] = __float2half(x[(8 * bh + r) * 512 + t]);
    xs4[flat] = u.v;
  }
  if (tid < 2) xs4[512 * 2 + tid] = make_float4(0.f, 0.f, 0.f, 0.f);

  int wave = tid >> 6, lane = tid & 63;
  int tl = lane >> 1, bh = lane & 1;
  // pos-major block -> entry-base permutation (LPT dispatch order)
  int b = blockIdx.x;
  int pos, seg;
  if (b < 80) { pos = b / 40;        seg = b % 40; }
  else        { int b2 = b - 80; pos = 2 + b2 / 39; seg = b2 % 39; }
  int ebase = seg * 256 + pos * 8;
  uint32_t e = entries[ebase + wave];
  int k = (int)(e >> 10);
  uint32_t bits = e & 1023u;
  __syncthreads();                   // the only barrier

  int ks  = 7 + 2 * (int)(bits & 3);
  int dil = (int)((bits >> 2) & 127);
  int pad = (int)(bits >> 9);
  int twop = (ks - 1) * dil * pad;
  int L = 512 + 2 * twop - dil * (ks - 1);
  float w10 = W[k * 11 + 10], w8 = W[k * 11 + 8];
  int ksW = (w10 != 0.0f) ? 11 : ((w8 != 0.0f) ? 9 : 7);
  if (failDiag != 0.0f || ks != ksW) {   // diag (never taken when correct)
    float diag = (failDiag != 0.0f) ? failDiag : 6500000.0f;
    if (lane < 16) {
      out[(size_t)lane * 20000 + 2 * k]     = diag;
      out[(size_t)lane * 20000 + 2 * k + 1] = diag;
    }
    return;
  }

  __half2 wh2[11];
  #pragma unroll
  for (int j = 0; j < 11; ++j) wh2[j] = __float2half2_rn(W[k * 11 + j]);
  __half2 bvh2 = __float2half2_rn(bias[k]);

  h2v mh[4];
  s2v ch[4];
  #pragma unroll
  for (int r = 0; r < 4; ++r) {
    mh[r] = (h2v)(-__builtin_huge_valf16());
    ch[r] = (s2v)0;
  }
  if (ks == 7)       conv_core<7>(xs4, wh2, bvh2, twop, dil, L, tl, bh, mh, ch);
  else if (ks == 9)  conv_core<9>(xs4, wh2, bvh2, twop, dil, L, tl, bh, mh, ch);
  else               conv_core<11>(xs4, wh2, bvh2, twop, dil, L, tl, bh, mh, ch);

  float m[8];
  int cn[8];
  #pragma unroll
  for (int r = 0; r < 4; ++r) {
    m[2 * r]      = (float)mh[r].x;
    m[2 * r + 1]  = (float)mh[r].y;
    cn[2 * r]     = (int)ch[r].x;
    cn[2 * r + 1] = (int)ch[r].y;
  }
  // reduce over tl (lane bits 1..5); bh (bit 0) preserved
  #pragma unroll
  for (int off = 2; off <= 32; off <<= 1) {
    #pragma unroll
    for (int r = 0; r < 8; ++r) {
      m[r] = fmaxf(m[r], __shfl_xor(m[r], off));
      cn[r] += __shfl_xor(cn[r], off);
    }
  }
  if (tl == 0) {                     // lanes 0,1 hold batches 8*bh + r
    float invL = 1.0f / (float)L;
    #pragma unroll
    for (int r = 0; r < 8; ++r) {
      size_t b2 = (size_t)(8 * bh + r);
      out[b2 * 20000 + 2 * k]     = m[r];
      out[b2 * 20000 + 2 * k + 1] = (float)cn[r] * invL;
    }
  }
}

extern "C" void kernel_launch(void* const* d_in, const int* in_sizes, int n_in,
                              void* d_out, int out_size, void* d_ws, size_t ws_size,
                              hipStream_t stream) {
  (void)out_size;
  const float *x = nullptr, *W = nullptr, *bias = nullptr;
  for (int i = 0; i < n_in; ++i) {
    int sz = in_sizes[i];
    if (sz == 16 * 512)      x    = (const float*)d_in[i];
    else if (sz == NK * 11)  W    = (const float*)d_in[i];
    else if (sz == NK)       bias = (const float*)d_in[i];
  }
  float failDiag = 0.0f;
  if (!x || !W || !bias) {
    failDiag = 9000000.0f;
    x = (const float*)d_in[0]; W = (const float*)d_in[1]; bias = (const float*)d_in[2];
  }

  // host stream for oracle + rejection check (off the timed path)
  static uint64_t hs[20000];
  {
    u128 st, inc; host_seed(st, inc);
    for (int i = 0; i < 20000; ++i) { st = st * PCG_MUL_128 + inc; hs[i] = xslrr_h(st); }
  }
  double d0 = (double)(hs[0] >> 11) * (1.0 / 9007199254740992.0);
  if (failDiag == 0.0f && fabs(d0 - 0.6369616873214543) >= 1.0e-15)
    failDiag = 4000000.0f;
  int rejected = 0;
  for (int i = 0; i < 5000; ++i)
    if ((uint32_t)hs[i] == 0u || (uint32_t)(hs[i] >> 32) == 0u) { rejected = 1; break; }

  // exact dil thresholds: t[si][v-2] = min d with pow(2, hi*d) >= v (glibc)
  static ThrTab tt;
  for (int si = 0; si < 3; ++si) {
    int ksv = 7 + 2 * si;
    double hi = log2((double)(511 / (ksv - 1)));
    double dmax = nextafter(1.0, 0.0);
    for (int v = 2; v <= 85; ++v) {
      if (pow(2.0, hi * dmax) < (double)v) { tt.t[si][v - 2] = 2.0; continue; }
      uint64_t lo = 0, hb;
      memcpy(&hb, &dmax, 8);
      while (hb - lo > 1) {
        uint64_t mid = lo + (hb - lo) / 2;
        double dm;
        memcpy(&dm, &mid, 8);
        if (pow(2.0, hi * dm) >= (double)v) hb = mid; else lo = mid;
      }
      double tv;
      memcpy(&tv, &hb, 8);
      tt.t[si][v - 2] = tv;
    }
  }

  uint32_t* dpack = (uint32_t*)d_ws;

  if (!rejected && ws_size >= WS_NEEDED) {
    params_k<<<(NK + 255) / 256, 256, 0, stream>>>(dpack, tt);
    conv_feat_k<<<NK / KPB, 512, 0, stream>>>(x, W, bias, dpack, failDiag,
                                              (float*)d_out);
  } else {
    // fallback (never for this seed): host pack + per-segment local sort
    // (matches params_k layout), one 40 KB H2D
    static uint32_t h_entries[NK];
    {
      int pos32 = 0;
      auto nx32 = [&](int& p) -> uint32_t {
        uint64_t v = hs[p >> 1];
        uint32_t u = (p & 1) ? (uint32_t)(v >> 32) : (uint32_t)v;
        ++p; return u;
      };
      static int ksA[NK], dilA[NK], padA[NK], LA[NK];
      for (int i = 0; i < NK; ++i) {
        uint64_t m; uint32_t u;
        do { u = nx32(pos32); m = (uint64_t)u * 3ull; } while ((uint32_t)m == 0u);
        ksA[i] = (int)(m >> 32);
      }
      int u64pos = (pos32 + 1) >> 1;
      for (int i = 0; i < NK; ++i) {
        double d = (double)(hs[u64pos + i] >> 11) * (1.0 / 9007199254740992.0);
        int ksv = 7 + 2 * ksA[i];
        double hi2 = log2((double)(511 / (ksv - 1)));
        dilA[i] = (int)floor(pow(2.0, hi2 * d));
      }
      int p32 = 2 * (u64pos + NK);
      for (int i = 0; i < NK; ++i) {
        padA[i] = (int)(nx32(p32) >> 31);
        int ksv = 7 + 2 * ksA[i];
        int twop = (ksv - 1) * dilA[i] * padA[i];
        LA[i] = 512 + 2 * twop - dilA[i] * (ksv - 1);
      }
      for (int base = 0; base < NK; base += 256) {
        int n = NK - base; if (n > 256) n = 256;
        static int cnt2[1024], off2[1024];
        for (int bb = 0; bb < 1024; ++bb) cnt2[bb] = 0;
        for (int j = 0; j < n; ++j) cnt2[1022 - LA[base + j]]++;
        int acc = 0;
        for (int bb = 0; bb < 1024; ++bb) { off2[bb] = acc; acc += cnt2[bb]; }
        for (int j = 0; j < n; ++j) {
          int i = base + j;
          uint32_t bits = (uint32_t)ksA[i] | ((uint32_t)dilA[i] << 2)
                        | ((uint32_t)padA[i] << 9);
          h_entries[base + off2[1022 - LA[i]]++] = ((uint32_t)i << 10) | bits;
        }
      }
    }
    (void)hipMemcpyAsync(dpack, h_entries, sizeof(h_entries),
                         hipMemcpyHostToDevice, stream);
    conv_feat_k<<<NK / KPB, 512, 0, stream>>>(x, W, bias, dpack, failDiag,
                                              (float*)d_out);
  }
}

// Round 29
// 60.166 us; speedup vs baseline: 1.5847x; 1.0287x over previous
//
#include <hip/hip_runtime.h>
#include <hip/hip_fp16.h>
#include <math.h>
#include <stdint.h>
#include <string.h>

typedef unsigned __int128 u128;
typedef _Float16 h2v __attribute__((ext_vector_type(2)));
typedef short    s2v __attribute__((ext_vector_type(2)));

#define NK 10000
#define KPB 8              // one k per wave; grid = NK/KPB = 1250

#define PCG_MUL_128 ((((u128)0x2360ed051fc65da4ULL) << 64) | 0x4385df649fccf645ULL)

#define WS_NEEDED  (NK * 4)

struct ThrTab { double t[3][84]; };        // dil thresholds, v = 2..85

// ============================================================================
// numpy default_rng(0) chain (verified r8-r28): SeedSequence mix = x*L - y*R
// (SUBTRACT); PCG64 XSL-RR step-then-output; integers -> buffered Lemire32,
// low half first. Device regenerates draws per-thread via advance() skip-ahead.
// ============================================================================
static void host_seed(u128& state, u128& inc) {
  uint32_t hc = 0x43b0d7e5u;
  auto hashmix = [&hc](uint32_t v) -> uint32_t {
    v ^= hc; hc *= 0x931e8875u; v *= hc; v ^= v >> 16; return v;
  };
  uint32_t pool[4];
  for (int i = 0; i < 4; ++i) pool[i] = hashmix(0u);
  for (int s = 0; s < 4; ++s)
    for (int d = 0; d < 4; ++d)
      if (s != d) {
        uint32_t h = hashmix(pool[s]);
        uint32_t r = pool[d] * 0xca01f9ddu - h * 0x4973f715u;   // subtract
        r ^= r >> 16;
        pool[d] = r;
      }
  uint32_t hb = 0x8b51f9ddu;
  uint32_t w[8];
  for (int i = 0; i < 8; ++i) {
    uint32_t v = pool[i & 3];
    v ^= hb; hb *= 0x58f38dedu; v *= hb; v ^= v >> 16;
    w[i] = v;
  }
  u128 is_ = ((u128)(((uint64_t)w[0]) | ((uint64_t)w[1] << 32)) << 64)
           | (u128)(((uint64_t)w[2]) | ((uint64_t)w[3] << 32));
  u128 iq  = ((u128)(((uint64_t)w[4]) | ((uint64_t)w[5] << 32)) << 64)
           | (u128)(((uint64_t)w[6]) | ((uint64_t)w[7] << 32));
  inc = (iq << 1) | (u128)1;
  state = inc; state += is_; state = state * PCG_MUL_128 + inc;
}

static inline uint64_t xslrr_h(u128 s) {
  uint64_t x = (uint64_t)(s >> 64) ^ (uint64_t)s;
  unsigned r = (unsigned)(s >> 122);
  return (x >> r) | (x << ((64u - r) & 63u));
}

__device__ __forceinline__ void dev_seed(u128& state, u128& inc) {
  uint32_t hc = 0x43b0d7e5u;
  auto hashmix = [&hc](uint32_t v) -> uint32_t {
    v ^= hc; hc *= 0x931e8875u; v *= hc; v ^= v >> 16; return v;
  };
  uint32_t pool[4];
  for (int i = 0; i < 4; ++i) pool[i] = hashmix(0u);
  for (int s = 0; s < 4; ++s)
    for (int d = 0; d < 4; ++d)
      if (s != d) {
        uint32_t h = hashmix(pool[s]);
        uint32_t r = pool[d] * 0xca01f9ddu - h * 0x4973f715u;   // subtract
        r ^= r >> 16;
        pool[d] = r;
      }
  uint32_t hb = 0x8b51f9ddu;
  uint32_t w[8];
  for (int i = 0; i < 8; ++i) {
    uint32_t v = pool[i & 3];
    v ^= hb; hb *= 0x58f38dedu; v *= hb; v ^= v >> 16;
    w[i] = v;
  }
  u128 is_ = ((u128)(((uint64_t)w[0]) | ((uint64_t)w[1] << 32)) << 64)
           | (u128)(((uint64_t)w[2]) | ((uint64_t)w[3] << 32));
  u128 iq  = ((u128)(((uint64_t)w[4]) | ((uint64_t)w[5] << 32)) << 64)
           | (u128)(((uint64_t)w[6]) | ((uint64_t)w[7] << 32));
  inc = (iq << 1) | (u128)1;
  state = inc; state += is_; state = state * PCG_MUL_128 + inc;
}

__device__ __forceinline__ u128 dev_advance(u128 state, u128 inc, uint64_t delta) {
  u128 am = 1, ap = 0, cm = PCG_MUL_128, cp = inc;
  while (delta) {
    if (delta & 1) { am = am * cm; ap = ap * cm + cp; }
    cp = (cm + (u128)1) * cp;
    cm = cm * cm;
    delta >>= 1;
  }
  return am * state + ap;
}

__device__ __forceinline__ uint64_t draw_at(u128 state, u128 inc, uint64_t n) {
  u128 s = dev_advance(state, inc, n);
  s = s * PCG_MUL_128 + inc;                // step-then-output
  uint64_t x = (uint64_t)(s >> 64) ^ (uint64_t)s;
  unsigned r = (unsigned)(s >> 122);
  return (x >> r) | (x << ((64u - r) & 63u));
}

// ============================================================================
// params_k (r27-proven): 40 blocks x 256, one entry per thread + block-local
// counting sort by L descending (hist + scan + scatter into pack segment).
// ============================================================================
__global__ __launch_bounds__(256) void params_k(uint32_t* __restrict__ pack,
                                                ThrTab tt) {
  __shared__ int hist[1024];
  __shared__ int scanbuf[256];
  __shared__ int offs[1024];
  int tid = threadIdx.x;
  int base = blockIdx.x * 256;
  int n = NK - base; if (n > 256) n = 256;

  uint32_t e = 0;
  int bkt = -1;
  if (tid < n) {
    int i = base + tid;
    u128 state, inc;
    dev_seed(state, inc);
    uint64_t a = draw_at(state, inc, (uint64_t)(i >> 1));
    uint32_t u = (i & 1) ? (uint32_t)(a >> 32) : (uint32_t)a;
    int si = (int)(((uint64_t)u * 3ull) >> 32);
    uint64_t ud = draw_at(state, inc, (uint64_t)(5000 + i));
    double d = (double)(ud >> 11) * (1.0 / 9007199254740992.0);
    int c0 = 0, c1 = 0, c2 = 0;
    #pragma unroll
    for (int v = 0; v < 84; ++v) {
      c0 += (d >= tt.t[0][v]) ? 1 : 0;
      c1 += (d >= tt.t[1][v]) ? 1 : 0;
      c2 += (d >= tt.t[2][v]) ? 1 : 0;
    }
    int dil = 1 + ((si == 0) ? c0 : ((si == 1) ? c1 : c2));
    uint64_t p6 = draw_at(state, inc, (uint64_t)(15000 + (i >> 1)));
    uint32_t pu = (i & 1) ? (uint32_t)(p6 >> 32) : (uint32_t)p6;
    int pad = (int)(pu >> 31);
    int ks = 7 + 2 * si;
    int twop = (ks - 1) * dil * pad;
    int L = 512 + 2 * twop - dil * (ks - 1);
    e = ((uint32_t)i << 10) | (uint32_t)si | ((uint32_t)dil << 2)
      | ((uint32_t)pad << 9);
    bkt = 1022 - L;                         // L in [2,1022] -> [0,1020]
  }
  #pragma unroll
  for (int q = 0; q < 4; ++q) hist[tid + 256 * q] = 0;
  __syncthreads();
  if (bkt >= 0) atomicAdd(&hist[bkt], 1);
  __syncthreads();
  int h0 = hist[4 * tid], h1 = hist[4 * tid + 1];
  int h2 = hist[4 * tid + 2], h3 = hist[4 * tid + 3];
  int s = h0 + h1 + h2 + h3;
  scanbuf[tid] = s;
  __syncthreads();
  for (int off = 1; off < 256; off <<= 1) {  // Hillis-Steele inclusive
    int v = (tid >= off) ? scanbuf[tid - off] : 0;
    __syncthreads();
    scanbuf[tid] += v;
    __syncthreads();
  }
  int ex = scanbuf[tid] - s;                 // exclusive prefix of group
  offs[4 * tid]     = ex;
  offs[4 * tid + 1] = ex + h0;
  offs[4 * tid + 2] = ex + h0 + h1;
  offs[4 * tid + 3] = ex + h0 + h1 + h2;
  __syncthreads();
  if (bkt >= 0) {
    int idx = atomicAdd(&offs[bkt], 1);
    pack[base + idx] = e;
  }
}

// ============================================================================
// Conv + max/ppv (r28 body + pair-chunk fast path): FP16-LDS xs[t][16b];
// lane (tl=lane>>1, bh=lane&1) reads float4 = 8 batches at one t. Fast
// region processes TWO chunks (t, t+32) per iteration: second read at
// constant +64 float4 offset (imm-folded), 2 independent MAC chains (ILP),
// loop/epilogue amortized 2x. All guards wave-uniform.
// ============================================================================
template<int KS>
__device__ __forceinline__ void conv_core(const float4* __restrict__ xs4,
                                          const __half2* wh2, __half2 bvh2,
                                          int twop, int dil, int L,
                                          int tl, int bh,
                                          h2v* mh, s2v* ch) {
  const h2v zero2 = (h2v)0;
  int coreEnd = (L < 512) ? L : 512;
  int nch = (L + 31) >> 5;
  int c = 0;
  while (c < nch) {
    int t0 = c << 5;
    int t = t0 + tl;
    if (t0 >= twop && t0 + 64 <= coreEnd && c + 1 < nch) {
      // pair fast path: chunks c, c+1 fully in-range; both t, t+32 < L
      __half2 a0[4], a1[4];
      #pragma unroll
      for (int r = 0; r < 4; ++r) { a0[r] = bvh2; a1[r] = bvh2; }
      const float4* p = xs4 + (unsigned)(t - twop) * 2 + bh;
      #pragma unroll
      for (int j = 0; j < KS; ++j) {
        float4 v4a = p[0];
        float4 v4b = p[64];                  // +32 t = +64 float4 (imm offset)
        union { float4 v; __half2 h[4]; } ua, ub;
        ua.v = v4a; ub.v = v4b;
        __half2 wj = wh2[j];
        #pragma unroll
        for (int r = 0; r < 4; ++r) {
          a0[r] = __hfma2(wj, ua.h[r], a0[r]);
          a1[r] = __hfma2(wj, ub.h[r], a1[r]);
        }
        p += (unsigned)dil * 2;
      }
      #pragma unroll
      for (int r = 0; r < 4; ++r) {
        union { __half2 h; h2v v; } c0v, c1v;
        c0v.h = a0[r]; c1v.h = a1[r];
        mh[r] = __builtin_elementwise_max(mh[r], c0v.v);
        ch[r] -= (c0v.v > zero2);
        mh[r] = __builtin_elementwise_max(mh[r], c1v.v);
        ch[r] -= (c1v.v > zero2);
      }
      c += 2;
      continue;
    }
    __half2 acc[4];
    #pragma unroll
    for (int r = 0; r < 4; ++r) acc[r] = bvh2;
    if (t0 >= twop && t0 + 32 <= coreEnd) {
      // single fast chunk
      const float4* p = xs4 + (unsigned)(t - twop) * 2 + bh;
      #pragma unroll
      for (int j = 0; j < KS; ++j) {
        float4 v4 = *p;
        union { float4 v; __half2 h[4]; } u;
        u.v = v4;
        __half2 wj = wh2[j];
        #pragma unroll
        for (int r = 0; r < 4; ++r) acc[r] = __hfma2(wj, u.h[r], acc[r]);
        p += (unsigned)dil * 2;
      }
    } else {
      // boundary chunk: umin clamp to zero row (negatives wrap -> 512)
      int idx = t - twop;
      #pragma unroll
      for (int j = 0; j < KS; ++j) {
        unsigned ci = (unsigned)idx;
        ci = (ci > 512u) ? 512u : ci;
        float4 v4 = xs4[ci * 2 + bh];
        union { float4 v; __half2 h[4]; } u;
        u.v = v4;
        __half2 wj = wh2[j];
        #pragma unroll
        for (int r = 0; r < 4; ++r) acc[r] = __hfma2(wj, u.h[r], acc[r]);
        idx += dil;
      }
    }
    if (t < L) {
      #pragma unroll
      for (int r = 0; r < 4; ++r) {
        union { __half2 h; h2v v; } cv;
        cv.h = acc[r];
        mh[r] = __builtin_elementwise_max(mh[r], cv.v);
        ch[r] -= (cv.v > zero2);             // mask = -1 per true -> +1
      }
    }
    c += 1;
  }
}

__global__ __launch_bounds__(512) void conv_feat_k(const float* __restrict__ x,
                                                   const float* __restrict__ W,
                                                   const float* __restrict__ bias,
                                                   const uint32_t* __restrict__ entries,
                                                   float failDiag,
                                                   float* __restrict__ out) {
  __shared__ float4 xs4[513 * 2];    // 16 halves per t; row 512 = zeros (16.4 KB)
  int tid = threadIdx.x;

  // stage batch-transposed fp16, once per block: flat = t*2 + bh
  #pragma unroll
  for (int q = 0; q < 2; ++q) {
    int flat = q * 512 + tid;        // 0..1023
    int t = flat >> 1, bh = flat & 1;
    union { __half h[8]; float4 v; } u;
    #pragma unroll
    for (int r = 0; r < 8; ++r)
      u.h[r] = __float2half(x[(8 * bh + r) * 512 + t]);
    xs4[flat] = u.v;
  }
  if (tid < 2) xs4[512 * 2 + tid] = make_float4(0.f, 0.f, 0.f, 0.f);

  int wave = tid >> 6, lane = tid & 63;
  int tl = lane >> 1, bh = lane & 1;
  // pos-major block -> entry-base permutation (LPT dispatch order, r28-proven)
  int b = blockIdx.x;
  int pos, seg;
  if (b < 80) { pos = b / 40;        seg = b % 40; }
  else        { int b2 = b - 80; pos = 2 + b2 / 39; seg = b2 % 39; }
  int ebase = seg * 256 + pos * 8;
  uint32_t e = entries[ebase + wave];
  int k = (int)(e >> 10);
  uint32_t bits = e & 1023u;
  __syncthreads();                   // the only barrier

  int ks  = 7 + 2 * (int)(bits & 3);
  int dil = (int)((bits >> 2) & 127);
  int pad = (int)(bits >> 9);
  int twop = (ks - 1) * dil * pad;
  int L = 512 + 2 * twop - dil * (ks - 1);
  float w10 = W[k * 11 + 10], w8 = W[k * 11 + 8];
  int ksW = (w10 != 0.0f) ? 11 : ((w8 != 0.0f) ? 9 : 7);
  if (failDiag != 0.0f || ks != ksW) {   // diag (never taken when correct)
    float diag = (failDiag != 0.0f) ? failDiag : 6500000.0f;
    if (lane < 16) {
      out[(size_t)lane * 20000 + 2 * k]     = diag;
      out[(size_t)lane * 20000 + 2 * k + 1] = diag;
    }
    return;
  }

  __half2 wh2[11];
  #pragma unroll
  for (int j = 0; j < 11; ++j) wh2[j] = __float2half2_rn(W[k * 11 + j]);
  __half2 bvh2 = __float2half2_rn(bias[k]);

  h2v mh[4];
  s2v ch[4];
  #pragma unroll
  for (int r = 0; r < 4; ++r) {
    mh[r] = (h2v)(-__builtin_huge_valf16());
    ch[r] = (s2v)0;
  }
  if (ks == 7)       conv_core<7>(xs4, wh2, bvh2, twop, dil, L, tl, bh, mh, ch);
  else if (ks == 9)  conv_core<9>(xs4, wh2, bvh2, twop, dil, L, tl, bh, mh, ch);
  else               conv_core<11>(xs4, wh2, bvh2, twop, dil, L, tl, bh, mh, ch);

  float m[8];
  int cn[8];
  #pragma unroll
  for (int r = 0; r < 4; ++r) {
    m[2 * r]      = (float)mh[r].x;
    m[2 * r + 1]  = (float)mh[r].y;
    cn[2 * r]     = (int)ch[r].x;
    cn[2 * r + 1] = (int)ch[r].y;
  }
  // reduce over tl (lane bits 1..5); bh (bit 0) preserved
  #pragma unroll
  for (int off = 2; off <= 32; off <<= 1) {
    #pragma unroll
    for (int r = 0; r < 8; ++r) {
      m[r] = fmaxf(m[r], __shfl_xor(m[r], off));
      cn[r] += __shfl_xor(cn[r], off);
    }
  }
  if (tl == 0) {                     // lanes 0,1 hold batches 8*bh + r
    float invL = 1.0f / (float)L;
    #pragma unroll
    for (int r = 0; r < 8; ++r) {
      size_t b2 = (size_t)(8 * bh + r);
      out[b2 * 20000 + 2 * k]     = m[r];
      out[b2 * 20000 + 2 * k + 1] = (float)cn[r] * invL;
    }
  }
}

extern "C" void kernel_launch(void* const* d_in, const int* in_sizes, int n_in,
                              void* d_out, int out_size, void* d_ws, size_t ws_size,
                              hipStream_t stream) {
  (void)out_size;
  const float *x = nullptr, *W = nullptr, *bias = nullptr;
  for (int i = 0; i < n_in; ++i) {
    int sz = in_sizes[i];
    if (sz == 16 * 512)      x    = (const float*)d_in[i];
    else if (sz == NK * 11)  W    = (const float*)d_in[i];
    else if (sz == NK)       bias = (const float*)d_in[i];
  }
  float failDiag = 0.0f;
  if (!x || !W || !bias) {
    failDiag = 9000000.0f;
    x = (const float*)d_in[0]; W = (const float*)d_in[1]; bias = (const float*)d_in[2];
  }

  // host stream for oracle + rejection check (off the timed path)
  static uint64_t hs[20000];
  {
    u128 st, inc; host_seed(st, inc);
    for (int i = 0; i < 20000; ++i) { st = st * PCG_MUL_128 + inc; hs[i] = xslrr_h(st); }
  }
  double d0 = (double)(hs[0] >> 11) * (1.0 / 9007199254740992.0);
  if (failDiag == 0.0f && fabs(d0 - 0.6369616873214543) >= 1.0e-15)
    failDiag = 4000000.0f;
  int rejected = 0;
  for (int i = 0; i < 5000; ++i)
    if ((uint32_t)hs[i] == 0u || (uint32_t)(hs[i] >> 32) == 0u) { rejected = 1; break; }

  // exact dil thresholds: t[si][v-2] = min d with pow(2, hi*d) >= v (glibc)
  static ThrTab tt;
  for (int si = 0; si < 3; ++si) {
    int ksv = 7 + 2 * si;
    double hi = log2((double)(511 / (ksv - 1)));
    double dmax = nextafter(1.0, 0.0);
    for (int v = 2; v <= 85; ++v) {
      if (pow(2.0, hi * dmax) < (double)v) { tt.t[si][v - 2] = 2.0; continue; }
      uint64_t lo = 0, hb;
      memcpy(&hb, &dmax, 8);
      while (hb - lo > 1) {
        uint64_t mid = lo + (hb - lo) / 2;
        double dm;
        memcpy(&dm, &mid, 8);
        if (pow(2.0, hi * dm) >= (double)v) hb = mid; else lo = mid;
      }
      double tv;
      memcpy(&tv, &hb, 8);
      tt.t[si][v - 2] = tv;
    }
  }

  uint32_t* dpack = (uint32_t*)d_ws;

  if (!rejected && ws_size >= WS_NEEDED) {
    params_k<<<(NK + 255) / 256, 256, 0, stream>>>(dpack, tt);
    conv_feat_k<<<NK / KPB, 512, 0, stream>>>(x, W, bias, dpack, failDiag,
                                              (float*)d_out);
  } else {
    // fallback (never for this seed): host pack + per-segment local sort
    // (matches params_k layout), one 40 KB H2D
    static uint32_t h_entries[NK];
    {
      int pos32 = 0;
      auto nx32 = [&](int& p) -> uint32_t {
        uint64_t v = hs[p >> 1];
        uint32_t u = (p & 1) ? (uint32_t)(v >> 32) : (uint32_t)v;
        ++p; return u;
      };
      static int ksA[NK], dilA[NK], padA[NK], LA[NK];
      for (int i = 0; i < NK; ++i) {
        uint64_t m; uint32_t u;
        do { u = nx32(pos32); m = (uint64_t)u * 3ull; } while ((uint32_t)m == 0u);
        ksA[i] = (int)(m >> 32);
      }
      int u64pos = (pos32 + 1) >> 1;
      for (int i = 0; i < NK; ++i) {
        double d = (double)(hs[u64pos + i] >> 11) * (1.0 / 9007199254740992.0);
        int ksv = 7 + 2 * ksA[i];
        double hi2 = log2((double)(511 / (ksv - 1)));
        dilA[i] = (int)floor(pow(2.0, hi2 * d));
      }
      int p32 = 2 * (u64pos + NK);
      for (int i = 0; i < NK; ++i) {
        padA[i] = (int)(nx32(p32) >> 31);
        int ksv = 7 + 2 * ksA[i];
        int twop = (ksv - 1) * dilA[i] * padA[i];
        LA[i] = 512 + 2 * twop - dilA[i] * (ksv - 1);
      }
      for (int base = 0; base < NK; base += 256) {
        int n = NK - base; if (n > 256) n = 256;
        static int cnt2[1024], off2[1024];
        for (int bb = 0; bb < 1024; ++bb) cnt2[bb] = 0;
        for (int j = 0; j < n; ++j) cnt2[1022 - LA[base + j]]++;
        int acc = 0;
        for (int bb = 0; bb < 1024; ++bb) { off2[bb] = acc; acc += cnt2[bb]; }
        for (int j = 0; j < n; ++j) {
          int i = base + j;
          uint32_t bits = (uint32_t)ksA[i] | ((uint32_t)dilA[i] << 2)
                        | ((uint32_t)padA[i] << 9);
          h_entries[base + off2[1022 - LA[i]]++] = ((uint32_t)i << 10) | bits;
        }
      }
    }
    (void)hipMemcpyAsync(dpack, h_entries, sizeof(h_entries),
                         hipMemcpyHostToDevice, stream);
    conv_feat_k<<<NK / KPB, 512, 0, stream>>>(x, W, bias, dpack, failDiag,
                                              (float*)d_out);
  }
}

// Round 30
// 60.127 us; speedup vs baseline: 1.5858x; 1.0006x over previous
//
#include <hip/hip_runtime.h>
#include <hip/hip_fp16.h>
#include <math.h>
#include <stdint.h>
#include <string.h>

typedef unsigned __int128 u128;
typedef _Float16 h2v __attribute__((ext_vector_type(2)));
typedef short    s2v __attribute__((ext_vector_type(2)));

#define NK 10000
#define KPB 8              // one k per wave; grid = NK/KPB = 1250

#define PCG_MUL_128 ((((u128)0x2360ed051fc65da4ULL) << 64) | 0x4385df649fccf645ULL)

#define WS_NEEDED  (NK * 4)

struct ThrTab { double t[3][84]; };        // dil thresholds, v = 2..85

// ============================================================================
// numpy default_rng(0) chain (verified r8-r29): SeedSequence mix = x*L - y*R
// (SUBTRACT); PCG64 XSL-RR step-then-output; integers -> buffered Lemire32,
// low half first. Device regenerates draws per-thread via advance() skip-ahead.
// ============================================================================
static void host_seed(u128& state, u128& inc) {
  uint32_t hc = 0x43b0d7e5u;
  auto hashmix = [&hc](uint32_t v) -> uint32_t {
    v ^= hc; hc *= 0x931e8875u; v *= hc; v ^= v >> 16; return v;
  };
  uint32_t pool[4];
  for (int i = 0; i < 4; ++i) pool[i] = hashmix(0u);
  for (int s = 0; s < 4; ++s)
    for (int d = 0; d < 4; ++d)
      if (s != d) {
        uint32_t h = hashmix(pool[s]);
        uint32_t r = pool[d] * 0xca01f9ddu - h * 0x4973f715u;   // subtract
        r ^= r >> 16;
        pool[d] = r;
      }
  uint32_t hb = 0x8b51f9ddu;
  uint32_t w[8];
  for (int i = 0; i < 8; ++i) {
    uint32_t v = pool[i & 3];
    v ^= hb; hb *= 0x58f38dedu; v *= hb; v ^= v >> 16;
    w[i] = v;
  }
  u128 is_ = ((u128)(((uint64_t)w[0]) | ((uint64_t)w[1] << 32)) << 64)
           | (u128)(((uint64_t)w[2]) | ((uint64_t)w[3] << 32));
  u128 iq  = ((u128)(((uint64_t)w[4]) | ((uint64_t)w[5] << 32)) << 64)
           | (u128)(((uint64_t)w[6]) | ((uint64_t)w[7] << 32));
  inc = (iq << 1) | (u128)1;
  state = inc; state += is_; state = state * PCG_MUL_128 + inc;
}

static inline uint64_t xslrr_h(u128 s) {
  uint64_t x = (uint64_t)(s >> 64) ^ (uint64_t)s;
  unsigned r = (unsigned)(s >> 122);
  return (x >> r) | (x << ((64u - r) & 63u));
}

__device__ __forceinline__ void dev_seed(u128& state, u128& inc) {
  uint32_t hc = 0x43b0d7e5u;
  auto hashmix = [&hc](uint32_t v) -> uint32_t {
    v ^= hc; hc *= 0x931e8875u; v *= hc; v ^= v >> 16; return v;
  };
  uint32_t pool[4];
  for (int i = 0; i < 4; ++i) pool[i] = hashmix(0u);
  for (int s = 0; s < 4; ++s)
    for (int d = 0; d < 4; ++d)
      if (s != d) {
        uint32_t h = hashmix(pool[s]);
        uint32_t r = pool[d] * 0xca01f9ddu - h * 0x4973f715u;   // subtract
        r ^= r >> 16;
        pool[d] = r;
      }
  uint32_t hb = 0x8b51f9ddu;
  uint32_t w[8];
  for (int i = 0; i < 8; ++i) {
    uint32_t v = pool[i & 3];
    v ^= hb; hb *= 0x58f38dedu; v *= hb; v ^= v >> 16;
    w[i] = v;
  }
  u128 is_ = ((u128)(((uint64_t)w[0]) | ((uint64_t)w[1] << 32)) << 64)
           | (u128)(((uint64_t)w[2]) | ((uint64_t)w[3] << 32));
  u128 iq  = ((u128)(((uint64_t)w[4]) | ((uint64_t)w[5] << 32)) << 64)
           | (u128)(((uint64_t)w[6]) | ((uint64_t)w[7] << 32));
  inc = (iq << 1) | (u128)1;
  state = inc; state += is_; state = state * PCG_MUL_128 + inc;
}

__device__ __forceinline__ u128 dev_advance(u128 state, u128 inc, uint64_t delta) {
  u128 am = 1, ap = 0, cm = PCG_MUL_128, cp = inc;
  while (delta) {
    if (delta & 1) { am = am * cm; ap = ap * cm + cp; }
    cp = (cm + (u128)1) * cp;
    cm = cm * cm;
    delta >>= 1;
  }
  return am * state + ap;
}

__device__ __forceinline__ uint64_t draw_at(u128 state, u128 inc, uint64_t n) {
  u128 s = dev_advance(state, inc, n);
  s = s * PCG_MUL_128 + inc;                // step-then-output
  uint64_t x = (uint64_t)(s >> 64) ^ (uint64_t)s;
  unsigned r = (unsigned)(s >> 122);
  return (x >> r) | (x << ((64u - r) & 63u));
}

// ============================================================================
// params_k (r27-proven): 40 blocks x 256, one entry per thread + block-local
// counting sort by L descending (hist + scan + scatter into pack segment).
// ============================================================================
__global__ __launch_bounds__(256) void params_k(uint32_t* __restrict__ pack,
                                                ThrTab tt) {
  __shared__ int hist[1024];
  __shared__ int scanbuf[256];
  __shared__ int offs[1024];
  int tid = threadIdx.x;
  int base = blockIdx.x * 256;
  int n = NK - base; if (n > 256) n = 256;

  uint32_t e = 0;
  int bkt = -1;
  if (tid < n) {
    int i = base + tid;
    u128 state, inc;
    dev_seed(state, inc);
    uint64_t a = draw_at(state, inc, (uint64_t)(i >> 1));
    uint32_t u = (i & 1) ? (uint32_t)(a >> 32) : (uint32_t)a;
    int si = (int)(((uint64_t)u * 3ull) >> 32);
    uint64_t ud = draw_at(state, inc, (uint64_t)(5000 + i));
    double d = (double)(ud >> 11) * (1.0 / 9007199254740992.0);
    int c0 = 0, c1 = 0, c2 = 0;
    #pragma unroll
    for (int v = 0; v < 84; ++v) {
      c0 += (d >= tt.t[0][v]) ? 1 : 0;
      c1 += (d >= tt.t[1][v]) ? 1 : 0;
      c2 += (d >= tt.t[2][v]) ? 1 : 0;
    }
    int dil = 1 + ((si == 0) ? c0 : ((si == 1) ? c1 : c2));
    uint64_t p6 = draw_at(state, inc, (uint64_t)(15000 + (i >> 1)));
    uint32_t pu = (i & 1) ? (uint32_t)(p6 >> 32) : (uint32_t)p6;
    int pad = (int)(pu >> 31);
    int ks = 7 + 2 * si;
    int twop = (ks - 1) * dil * pad;
    int L = 512 + 2 * twop - dil * (ks - 1);
    e = ((uint32_t)i << 10) | (uint32_t)si | ((uint32_t)dil << 2)
      | ((uint32_t)pad << 9);
    bkt = 1022 - L;                         // L in [2,1022] -> [0,1020]
  }
  #pragma unroll
  for (int q = 0; q < 4; ++q) hist[tid + 256 * q] = 0;
  __syncthreads();
  if (bkt >= 0) atomicAdd(&hist[bkt], 1);
  __syncthreads();
  int h0 = hist[4 * tid], h1 = hist[4 * tid + 1];
  int h2 = hist[4 * tid + 2], h3 = hist[4 * tid + 3];
  int s = h0 + h1 + h2 + h3;
  scanbuf[tid] = s;
  __syncthreads();
  for (int off = 1; off < 256; off <<= 1) {  // Hillis-Steele inclusive
    int v = (tid >= off) ? scanbuf[tid - off] : 0;
    __syncthreads();
    scanbuf[tid] += v;
    __syncthreads();
  }
  int ex = scanbuf[tid] - s;                 // exclusive prefix of group
  offs[4 * tid]     = ex;
  offs[4 * tid + 1] = ex + h0;
  offs[4 * tid + 2] = ex + h0 + h1;
  offs[4 * tid + 3] = ex + h0 + h1 + h2;
  __syncthreads();
  if (bkt >= 0) {
    int idx = atomicAdd(&offs[bkt], 1);
    pack[base + idx] = e;
  }
}

// ============================================================================
// Conv + max/ppv (r29 body + quad-chunk fast path): FP16-LDS xs[t][16b];
// lane (tl=lane>>1, bh=lane&1) reads float4 = 8 batches at one t. Fast
// region processes FOUR chunks (t..t+96) per iteration: reads at constant
// +64/+128/+192 float4 offsets (imm-folded), 4 independent MAC chains.
// Cascade quad -> pair -> single -> boundary; guards wave-uniform.
// ============================================================================
template<int KS>
__device__ __forceinline__ void conv_core(const float4* __restrict__ xs4,
                                          const __half2* wh2, __half2 bvh2,
                                          int twop, int dil, int L,
                                          int tl, int bh,
                                          h2v* mh, s2v* ch) {
  const h2v zero2 = (h2v)0;
  int coreEnd = (L < 512) ? L : 512;
  int nch = (L + 31) >> 5;
  int c = 0;
  while (c < nch) {
    int t0 = c << 5;
    int t = t0 + tl;
    if (t0 >= twop && t0 + 128 <= coreEnd && c + 3 < nch) {
      // quad fast path: chunks c..c+3 fully in-range; t..t+96 < L
      __half2 a0[4], a1[4], a2[4], a3[4];
      #pragma unroll
      for (int r = 0; r < 4; ++r) { a0[r] = bvh2; a1[r] = bvh2; a2[r] = bvh2; a3[r] = bvh2; }
      const float4* p = xs4 + (unsigned)(t - twop) * 2 + bh;
      #pragma unroll
      for (int j = 0; j < KS; ++j) {
        float4 va = p[0], vb = p[64], vc = p[128], vd = p[192];
        union { float4 v; __half2 h[4]; } ua, ub, uc, ud;
        ua.v = va; ub.v = vb; uc.v = vc; ud.v = vd;
        __half2 wj = wh2[j];
        #pragma unroll
        for (int r = 0; r < 4; ++r) {
          a0[r] = __hfma2(wj, ua.h[r], a0[r]);
          a1[r] = __hfma2(wj, ub.h[r], a1[r]);
          a2[r] = __hfma2(wj, uc.h[r], a2[r]);
          a3[r] = __hfma2(wj, ud.h[r], a3[r]);
        }
        p += (unsigned)dil * 2;
      }
      #pragma unroll
      for (int r = 0; r < 4; ++r) {
        union { __half2 h; h2v v; } v0, v1, v2, v3;
        v0.h = a0[r]; v1.h = a1[r]; v2.h = a2[r]; v3.h = a3[r];
        mh[r] = __builtin_elementwise_max(mh[r], v0.v); ch[r] -= (v0.v > zero2);
        mh[r] = __builtin_elementwise_max(mh[r], v1.v); ch[r] -= (v1.v > zero2);
        mh[r] = __builtin_elementwise_max(mh[r], v2.v); ch[r] -= (v2.v > zero2);
        mh[r] = __builtin_elementwise_max(mh[r], v3.v); ch[r] -= (v3.v > zero2);
      }
      c += 4;
      continue;
    }
    if (t0 >= twop && t0 + 64 <= coreEnd && c + 1 < nch) {
      // pair fast path (r29-proven)
      __half2 a0[4], a1[4];
      #pragma unroll
      for (int r = 0; r < 4; ++r) { a0[r] = bvh2; a1[r] = bvh2; }
      const float4* p = xs4 + (unsigned)(t - twop) * 2 + bh;
      #pragma unroll
      for (int j = 0; j < KS; ++j) {
        float4 v4a = p[0];
        float4 v4b = p[64];
        union { float4 v; __half2 h[4]; } ua, ub;
        ua.v = v4a; ub.v = v4b;
        __half2 wj = wh2[j];
        #pragma unroll
        for (int r = 0; r < 4; ++r) {
          a0[r] = __hfma2(wj, ua.h[r], a0[r]);
          a1[r] = __hfma2(wj, ub.h[r], a1[r]);
        }
        p += (unsigned)dil * 2;
      }
      #pragma unroll
      for (int r = 0; r < 4; ++r) {
        union { __half2 h; h2v v; } c0v, c1v;
        c0v.h = a0[r]; c1v.h = a1[r];
        mh[r] = __builtin_elementwise_max(mh[r], c0v.v);
        ch[r] -= (c0v.v > zero2);
        mh[r] = __builtin_elementwise_max(mh[r], c1v.v);
        ch[r] -= (c1v.v > zero2);
      }
      c += 2;
      continue;
    }
    __half2 acc[4];
    #pragma unroll
    for (int r = 0; r < 4; ++r) acc[r] = bvh2;
    if (t0 >= twop && t0 + 32 <= coreEnd) {
      // single fast chunk
      const float4* p = xs4 + (unsigned)(t - twop) * 2 + bh;
      #pragma unroll
      for (int j = 0; j < KS; ++j) {
        float4 v4 = *p;
        union { float4 v; __half2 h[4]; } u;
        u.v = v4;
        __half2 wj = wh2[j];
        #pragma unroll
        for (int r = 0; r < 4; ++r) acc[r] = __hfma2(wj, u.h[r], acc[r]);
        p += (unsigned)dil * 2;
      }
    } else {
      // boundary chunk: umin clamp to zero row (negatives wrap -> 512)
      int idx = t - twop;
      #pragma unroll
      for (int j = 0; j < KS; ++j) {
        unsigned ci = (unsigned)idx;
        ci = (ci > 512u) ? 512u : ci;
        float4 v4 = xs4[ci * 2 + bh];
        union { float4 v; __half2 h[4]; } u;
        u.v = v4;
        __half2 wj = wh2[j];
        #pragma unroll
        for (int r = 0; r < 4; ++r) acc[r] = __hfma2(wj, u.h[r], acc[r]);
        idx += dil;
      }
    }
    if (t < L) {
      #pragma unroll
      for (int r = 0; r < 4; ++r) {
        union { __half2 h; h2v v; } cv;
        cv.h = acc[r];
        mh[r] = __builtin_elementwise_max(mh[r], cv.v);
        ch[r] -= (cv.v > zero2);             // mask = -1 per true -> +1
      }
    }
    c += 1;
  }
}

__global__ __launch_bounds__(512) void conv_feat_k(const float* __restrict__ x,
                                                   const float* __restrict__ W,
                                                   const float* __restrict__ bias,
                                                   const uint32_t* __restrict__ entries,
                                                   float failDiag,
                                                   float* __restrict__ out) {
  __shared__ float4 xs4[513 * 2];    // 16 halves per t; row 512 = zeros (16.4 KB)
  int tid = threadIdx.x;

  // stage batch-transposed fp16, once per block: flat = t*2 + bh
  #pragma unroll
  for (int q = 0; q < 2; ++q) {
    int flat = q * 512 + tid;        // 0..1023
    int t = flat >> 1, bh = flat & 1;
    union { __half h[8]; float4 v; } u;
    #pragma unroll
    for (int r = 0; r < 8; ++r)
      u.h[r] = __float2half(x[(8 * bh + r) * 512 + t]);
    xs4[flat] = u.v;
  }
  if (tid < 2) xs4[512 * 2 + tid] = make_float4(0.f, 0.f, 0.f, 0.f);

  int wave = tid >> 6, lane = tid & 63;
  int tl = lane >> 1, bh = lane & 1;
  // pos-major block -> entry-base permutation (LPT dispatch order, r28-proven)
  int b = blockIdx.x;
  int pos, seg;
  if (b < 80) { pos = b / 40;        seg = b % 40; }
  else        { int b2 = b - 80; pos = 2 + b2 / 39; seg = b2 % 39; }
  int ebase = seg * 256 + pos * 8;
  uint32_t e = entries[ebase + wave];
  int k = (int)(e >> 10);
  uint32_t bits = e & 1023u;
  __syncthreads();                   // the only barrier

  int ks  = 7 + 2 * (int)(bits & 3);
  int dil = (int)((bits >> 2) & 127);
  int pad = (int)(bits >> 9);
  int twop = (ks - 1) * dil * pad;
  int L = 512 + 2 * twop - dil * (ks - 1);
  float w10 = W[k * 11 + 10], w8 = W[k * 11 + 8];
  int ksW = (w10 != 0.0f) ? 11 : ((w8 != 0.0f) ? 9 : 7);
  if (failDiag != 0.0f || ks != ksW) {   // diag (never taken when correct)
    float diag = (failDiag != 0.0f) ? failDiag : 6500000.0f;
    if (lane < 16) {
      out[(size_t)lane * 20000 + 2 * k]     = diag;
      out[(size_t)lane * 20000 + 2 * k + 1] = diag;
    }
    return;
  }

  __half2 wh2[11];
  #pragma unroll
  for (int j = 0; j < 11; ++j) wh2[j] = __float2half2_rn(W[k * 11 + j]);
  __half2 bvh2 = __float2half2_rn(bias[k]);

  h2v mh[4];
  s2v ch[4];
  #pragma unroll
  for (int r = 0; r < 4; ++r) {
    mh[r] = (h2v)(-__builtin_huge_valf16());
    ch[r] = (s2v)0;
  }
  if (ks == 7)       conv_core<7>(xs4, wh2, bvh2, twop, dil, L, tl, bh, mh, ch);
  else if (ks == 9)  conv_core<9>(xs4, wh2, bvh2, twop, dil, L, tl, bh, mh, ch);
  else               conv_core<11>(xs4, wh2, bvh2, twop, dil, L, tl, bh, mh, ch);

  float m[8];
  int cn[8];
  #pragma unroll
  for (int r = 0; r < 4; ++r) {
    m[2 * r]      = (float)mh[r].x;
    m[2 * r + 1]  = (float)mh[r].y;
    cn[2 * r]     = (int)ch[r].x;
    cn[2 * r + 1] = (int)ch[r].y;
  }
  // reduce over tl (lane bits 1..5); bh (bit 0) preserved
  #pragma unroll
  for (int off = 2; off <= 32; off <<= 1) {
    #pragma unroll
    for (int r = 0; r < 8; ++r) {
      m[r] = fmaxf(m[r], __shfl_xor(m[r], off));
      cn[r] += __shfl_xor(cn[r], off);
    }
  }
  if (tl == 0) {                     // lanes 0,1 hold batches 8*bh + r
    float invL = 1.0f / (float)L;
    #pragma unroll
    for (int r = 0; r < 8; ++r) {
      size_t b2 = (size_t)(8 * bh + r);
      out[b2 * 20000 + 2 * k]     = m[r];
      out[b2 * 20000 + 2 * k + 1] = (float)cn[r] * invL;
    }
  }
}

extern "C" void kernel_launch(void* const* d_in, const int* in_sizes, int n_in,
                              void* d_out, int out_size, void* d_ws, size_t ws_size,
                              hipStream_t stream) {
  (void)out_size;
  const float *x = nullptr, *W = nullptr, *bias = nullptr;
  for (int i = 0; i < n_in; ++i) {
    int sz = in_sizes[i];
    if (sz == 16 * 512)      x    = (const float*)d_in[i];
    else if (sz == NK * 11)  W    = (const float*)d_in[i];
    else if (sz == NK)       bias = (const float*)d_in[i];
  }
  float failDiag = 0.0f;
  if (!x || !W || !bias) {
    failDiag = 9000000.0f;
    x = (const float*)d_in[0]; W = (const float*)d_in[1]; bias = (const float*)d_in[2];
  }

  // host stream for oracle + rejection check (off the timed path)
  static uint64_t hs[20000];
  {
    u128 st, inc; host_seed(st, inc);
    for (int i = 0; i < 20000; ++i) { st = st * PCG_MUL_128 + inc; hs[i] = xslrr_h(st); }
  }
  double d0 = (double)(hs[0] >> 11) * (1.0 / 9007199254740992.0);
  if (failDiag == 0.0f && fabs(d0 - 0.6369616873214543) >= 1.0e-15)
    failDiag = 4000000.0f;
  int rejected = 0;
  for (int i = 0; i < 5000; ++i)
    if ((uint32_t)hs[i] == 0u || (uint32_t)(hs[i] >> 32) == 0u) { rejected = 1; break; }

  // exact dil thresholds: t[si][v-2] = min d with pow(2, hi*d) >= v (glibc)
  static ThrTab tt;
  for (int si = 0; si < 3; ++si) {
    int ksv = 7 + 2 * si;
    double hi = log2((double)(511 / (ksv - 1)));
    double dmax = nextafter(1.0, 0.0);
    for (int v = 2; v <= 85; ++v) {
      if (pow(2.0, hi * dmax) < (double)v) { tt.t[si][v - 2] = 2.0; continue; }
      uint64_t lo = 0, hb;
      memcpy(&hb, &dmax, 8);
      while (hb - lo > 1) {
        uint64_t mid = lo + (hb - lo) / 2;
        double dm;
        memcpy(&dm, &mid, 8);
        if (pow(2.0, hi * dm) >= (double)v) hb = mid; else lo = mid;
      }
      double tv;
      memcpy(&tv, &hb, 8);
      tt.t[si][v - 2] = tv;
    }
  }

  uint32_t* dpack = (uint32_t*)d_ws;

  if (!rejected && ws_size >= WS_NEEDED) {
    params_k<<<(NK + 255) / 256, 256, 0, stream>>>(dpack, tt);
    conv_feat_k<<<NK / KPB, 512, 0, stream>>>(x, W, bias, dpack, failDiag,
                                              (float*)d_out);
  } else {
    // fallback (never for this seed): host pack + per-segment local sort
    // (matches params_k layout), one 40 KB H2D
    static uint32_t h_entries[NK];
    {
      int pos32 = 0;
      auto nx32 = [&](int& p) -> uint32_t {
        uint64_t v = hs[p >> 1];
        uint32_t u = (p & 1) ? (uint32_t)(v >> 32) : (uint32_t)v;
        ++p; return u;
      };
      static int ksA[NK], dilA[NK], padA[NK], LA[NK];
      for (int i = 0; i < NK; ++i) {
        uint64_t m; uint32_t u;
        do { u = nx32(pos32); m = (uint64_t)u * 3ull; } while ((uint32_t)m == 0u);
        ksA[i] = (int)(m >> 32);
      }
      int u64pos = (pos32 + 1) >> 1;
      for (int i = 0; i < NK; ++i) {
        double d = (double)(hs[u64pos + i] >> 11) * (1.0 / 9007199254740992.0);
        int ksv = 7 + 2 * ksA[i];
        double hi2 = log2((double)(511 / (ksv - 1)));
        dilA[i] = (int)floor(pow(2.0, hi2 * d));
      }
      int p32 = 2 * (u64pos + NK);
      for (int i = 0; i < NK; ++i) {
        padA[i] = (int)(nx32(p32) >> 31);
        int ksv = 7 + 2 * ksA[i];
        int twop = (ksv - 1) * dilA[i] * padA[i];
        LA[i] = 512 + 2 * twop - dilA[i] * (ksv - 1);
      }
      for (int base = 0; base < NK; base += 256) {
        int n = NK - base; if (n > 256) n = 256;
        static int cnt2[1024], off2[1024];
        for (int bb = 0; bb < 1024; ++bb) cnt2[bb] = 0;
        for (int j = 0; j < n; ++j) cnt2[1022 - LA[base + j]]++;
        int acc = 0;
        for (int bb = 0; bb < 1024; ++bb) { off2[bb] = acc; acc += cnt2[bb]; }
        for (int j = 0; j < n; ++j) {
          int i = base + j;
          uint32_t bits = (uint32_t)ksA[i] | ((uint32_t)dilA[i] << 2)
                        | ((uint32_t)padA[i] << 9);
          h_entries[base + off2[1022 - LA[i]]++] = ((uint32_t)i << 10) | bits;
        }
      }
    }
    (void)hipMemcpyAsync(dpack, h_entries, sizeof(h_entries),
                         hipMemcpyHostToDevice, stream);
    conv_feat_k<<<NK / KPB, 512, 0, stream>>>(x, W, bias, dpack, failDiag,
                                              (float*)d_out);
  }
}